// Round 3
// baseline (39.277 us; speedup 1.0000x reference)
//
#include <hip/hip_runtime.h>

#define NN 16384
#define NT 1024
#define PER 16
#define KWIN 4

__global__ __launch_bounds__(NT) void dag_eval_kernel(
    const int* __restrict__ left,
    const int* __restrict__ right,
    const unsigned char* __restrict__ reroll_raw,
    int* __restrict__ out)
{
    __shared__ unsigned char reach[NN];        // 0/1 bytes
    __shared__ unsigned char state[NN + 16];   // hs | hr<<1 | final<<2 ; [NN..] = 4 (final, no bits)
    __shared__ int flags[2];
    __shared__ int nzmask;
    __shared__ int cnt;

    const int tid = threadIdx.x;
    const int b0  = tid * PER;

    if (tid == 0) { nzmask = 0; cnt = 0; flags[0] = 0; flags[1] = 0; }
    if (tid < 16) state[NN + tid] = 4;

    // ---- children, coalesced int4 loads ----
    int lch[PER], rch[PER];
    {
        const int4* l4 = (const int4*)left;
        const int4* r4 = (const int4*)right;
        #pragma unroll
        for (int j = 0; j < PER / 4; ++j) {
            int4 a = l4[(b0 >> 2) + j];
            int4 b = r4[(b0 >> 2) + j];
            lch[4*j+0] = a.x; lch[4*j+1] = a.y; lch[4*j+2] = a.z; lch[4*j+3] = a.w;
            rch[4*j+0] = b.x; rch[4*j+1] = b.y; rch[4*j+2] = b.z; rch[4*j+3] = b.w;
        }
    }

    // ---- leaf_is_reroll layout detection (first 16 KB, safe all layouts) ----
    {
        uint4 v = ((const uint4*)reroll_raw)[tid];
        unsigned int t = v.x | v.y | v.z | v.w;
        unsigned int m = 0;
        if (t & 0x000000FFu) m |= 1u;
        if (t & 0x0000FF00u) m |= 2u;
        if (t & 0x00FF0000u) m |= 4u;
        if (t & 0xFF000000u) m |= 8u;
        if (m) atomicOr(&nzmask, (int)m);
    }

    *(uint4*)&reach[b0] = make_uint4(0u, 0u, 0u, 0u);
    __syncthreads();

    const int mask   = nzmask;
    const int layout = ((mask & ~1) == 0) ? 0 : (((mask & 3) == 0) ? 1 : 2);
    const int*   ri = (const int*)reroll_raw;
    const float* rf = (const float*)reroll_raw;

    // ---- init backward state; final if both children leaves (covers s==3) ----
    int sreg[PER];
    unsigned int todo = 0;
    #pragma unroll
    for (int k = 0; k < PER; ++k) {
        int s = 0;
        int l = lch[k], r = rch[k];
        if (l < 0) {
            int id = -l - 1;
            bool rr = (layout == 2) ? (reroll_raw[id] != 0)
                     : (layout == 1) ? (rf[id] != 0.0f)
                                     : (ri[id] != 0);
            s |= rr ? 2 : 1;
        }
        if (r < 0) {
            int id = -r - 1;
            bool rr = (layout == 2) ? (reroll_raw[id] != 0)
                     : (layout == 1) ? (rf[id] != 0.0f)
                                     : (ri[id] != 0);
            s |= rr ? 2 : 1;
        }
        if ((l < 0 && r < 0) || s == 3) s |= 4;       // final
        else todo |= 1u << k;
        sreg[k] = s;
        state[b0 + k] = (unsigned char)s;
    }
    if (tid == 0) reach[0] = 1;
    __syncthreads();

    // ---- merged fixpoint: forward push-once + backward pull, windowed ----
    unsigned int pushed = 0, mm = 0;
    for (int w = 0; ; ++w) {
        bool ch = false;
        for (int it = 0; it < KWIN; ++it) {
            bool c2 = false;
            // forward: one ds_read_b128 + movemask + push-once
            uint4 rv = *(const uint4*)&reach[b0];
            mm  =  ((rv.x * 0x01020408u) >> 24) & 0xFu;
            mm |= (((rv.y * 0x01020408u) >> 24) & 0xFu) << 4;
            mm |= (((rv.z * 0x01020408u) >> 24) & 0xFu) << 8;
            mm |= (((rv.w * 0x01020408u) >> 24) & 0xFu) << 12;
            unsigned int newp = mm & ~pushed;
            pushed |= newp;
            if (newp) c2 = true;
            while (newp) {
                int k = __builtin_ctz(newp);
                newp &= newp - 1u;
                int c = lch[k]; if (c >= 0) reach[c] = (unsigned char)1;
                c = rch[k];     if (c >= 0) reach[c] = (unsigned char)1;
            }
            // backward: branchless gather (ILP), finalize via bit2
            if (todo) {
                int tl[PER], tr[PER];
                #pragma unroll
                for (int k = 0; k < PER; ++k) {
                    bool act = (todo >> k) & 1u;
                    int la = (act && lch[k] >= 0) ? lch[k] : NN;
                    int ra = (act && rch[k] >= 0) ? rch[k] : NN;
                    tl[k] = state[la];
                    tr[k] = state[ra];
                }
                #pragma unroll
                for (int k = 0; k < PER; ++k) {
                    if ((todo >> k) & 1u) {
                        int sl = tl[k], sr = tr[k];
                        int ns = sreg[k] | (sl & 3) | (sr & 3);
                        if (((sl & sr) & 4) || (ns & 3) == 3) {
                            ns |= 4;
                            todo &= ~(1u << k);
                            sreg[k] = ns;
                            state[b0 + k] = (unsigned char)ns;
                            c2 = true;
                        } else if (ns != sreg[k]) {
                            sreg[k] = ns;
                            state[b0 + k] = (unsigned char)ns;
                            c2 = true;
                        }
                    }
                }
            }
            ch |= c2;
            if (!c2) break;
        }
        int p = w & 1;
        if (ch) flags[p] = 1;
        __syncthreads();
        int f = flags[p];
        if (tid == 0) flags[p ^ 1] = 0;
        __syncthreads();
        if (!f) break;
    }

    // ---- count: wave shuffle reduce, one atomic per wave ----
    int cc = __popc(mm);
    #pragma unroll
    for (int off = 32; off; off >>= 1) cc += __shfl_down(cc, off);
    if ((tid & 63) == 0) atomicAdd(&cnt, cc);

    // ---- outputs from registers, int4 stores ----
    int4* out4 = (int4*)out;
    #pragma unroll
    for (int j = 0; j < PER / 4; ++j) {
        int4 a, h, r;
        a.x = (mm >> (4*j+0)) & 1; a.y = (mm >> (4*j+1)) & 1;
        a.z = (mm >> (4*j+2)) & 1; a.w = (mm >> (4*j+3)) & 1;
        h.x =  sreg[4*j+0] & 1;       h.y =  sreg[4*j+1] & 1;
        h.z =  sreg[4*j+2] & 1;       h.w =  sreg[4*j+3] & 1;
        r.x = (sreg[4*j+0] >> 1) & 1; r.y = (sreg[4*j+1] >> 1) & 1;
        r.z = (sreg[4*j+2] >> 1) & 1; r.w = (sreg[4*j+3] >> 1) & 1;
        out4[(b0 >> 2) + j]              = a;
        out4[((NN + b0) >> 2) + j]       = h;
        out4[((2 * NN + b0) >> 2) + j]   = r;
    }
    __syncthreads();
    if (tid == 0) out[3 * NN] = cnt;
}

extern "C" void kernel_launch(void* const* d_in, const int* in_sizes, int n_in,
                              void* d_out, int out_size, void* d_ws, size_t ws_size,
                              hipStream_t stream)
{
    const int* left  = (const int*)d_in[3];
    const int* right = (const int*)d_in[4];
    const unsigned char* reroll = (const unsigned char*)d_in[5];
    int* out = (int*)d_out;
    dag_eval_kernel<<<1, NT, 0, stream>>>(left, right, reroll, out);
}